// Round 2
// baseline (798.698 us; speedup 1.0000x reference)
//
#include <hip/hip_runtime.h>
#include <math.h>

// Problem constants (from reference)
#define NSENT 131072
#define NBAGS 8192
#define DIM   690
#define NCLS  53
#define PAIRS 345   // DIM/2 (rows are 8B-aligned: 690*4 = 2760 % 8 == 0)

// ---------------------------------------------------------------------------
// K1: comb[q][d] = attention_weight[q][d] * relation_weight[q][d]
// ---------------------------------------------------------------------------
__global__ void comb_kernel(const float* __restrict__ att,
                            const float* __restrict__ rel,
                            float* __restrict__ comb) {
    int i = blockIdx.x * 256 + threadIdx.x;
    if (i < NCLS * DIM) comb[i] = att[i] * rel[i];
}

// ---------------------------------------------------------------------------
// K2: one bag per WAVE. Flash online softmax over the bag's sentences,
// x row held in registers (6 float2/lane), explicit next-row prefetch.
// No LDS, no barriers -> pure streaming. Writes normalized bag_repre to ws.
// __launch_bounds__(256,8): force VGPR<=64 so all 8192 waves are resident.
// ---------------------------------------------------------------------------
__global__ __launch_bounds__(256, 8) void bag_stream_kernel(
        const float* __restrict__ x,
        const float* __restrict__ comb,
        const int*   __restrict__ query,
        const int*   __restrict__ scope,
        float*       __restrict__ repre) {
    const int bag  = blockIdx.x * 4 + (threadIdx.x >> 6);
    const int lane = threadIdx.x & 63;
    const int start = scope[bag];
    const int end   = scope[bag + 1];

    float2 acc[6];
#pragma unroll
    for (int k = 0; k < 6; ++k) acc[k] = make_float2(0.f, 0.f);
    float m = -INFINITY;
    float l = 0.f;

    // prefetch first row
    int q = query[start];
    float2 xv[6];
    {
        const float2* xrow = (const float2*)(x + (size_t)start * DIM);
#pragma unroll
        for (int k = 0; k < 6; ++k) {
            const int p = lane + 64 * k;
            xv[k] = (p < PAIRS) ? xrow[p] : make_float2(0.f, 0.f);
        }
    }

    for (int i = start; i < end; ++i) {
        // dot(x_i, comb[q_i]) — comb rows are L2-hot
        const float2* crow = (const float2*)(comb + (size_t)q * DIM);
        float partial = 0.f;
#pragma unroll
        for (int k = 0; k < 6; ++k) {
            const int p = lane + 64 * k;
            if (p < PAIRS) {
                const float2 cv = crow[p];
                partial += xv[k].x * cv.x + xv[k].y * cv.y;
            }
        }

        // prefetch next row while the reduce chain runs
        float2 xn[6];
        int qn = 0;
        const bool more = (i + 1 < end);
        if (more) {
            qn = query[i + 1];
            const float2* xrow = (const float2*)(x + (size_t)(i + 1) * DIM);
#pragma unroll
            for (int k = 0; k < 6; ++k) {
                const int p = lane + 64 * k;
                xn[k] = (p < PAIRS) ? xrow[p] : make_float2(0.f, 0.f);
            }
        } else {
#pragma unroll
            for (int k = 0; k < 6; ++k) xn[k] = make_float2(0.f, 0.f);
        }

        // wave-wide sum (64 lanes)
#pragma unroll
        for (int off = 32; off >= 1; off >>= 1)
            partial += __shfl_xor(partial, off, 64);

        // online softmax update (__expf(-inf) == 0 covers the first iter)
        const float mn = fmaxf(m, partial);
        const float sc = __expf(m - mn);
        const float e  = __expf(partial - mn);
        l = l * sc + e;
#pragma unroll
        for (int k = 0; k < 6; ++k) {
            acc[k].x = acc[k].x * sc + e * xv[k].x;
            acc[k].y = acc[k].y * sc + e * xv[k].y;
        }
        m = mn;

#pragma unroll
        for (int k = 0; k < 6; ++k) xv[k] = xn[k];
        q = qn;
    }

    // normalize and store bag representation (every bag has >=1 sentence)
    const float inv = 1.f / l;
    float2* rrow = (float2*)(repre + (size_t)bag * DIM);
#pragma unroll
    for (int k = 0; k < 6; ++k) {
        const int p = lane + 64 * k;
        if (p < PAIRS)
            rrow[p] = make_float2(acc[k].x * inv, acc[k].y * inv);
    }
}

// ---------------------------------------------------------------------------
// K3: out[b][c] = dot(repre[b], rel[c]) + bias[c]
// Tiled: 32 bags/block, rel staged in LDS in 3 chunks of [53][230] (48.8 KB).
// Thread t: bag_l = t>>3, class offset co = t&7, classes c = co + 8k (k<7).
// LDS pattern: 8 distinct rows x broadcast across 8 bag-lanes -> conflict-free.
// ---------------------------------------------------------------------------
#define K3_BPB 32   // bags per block
#define K3_CD  230  // d-chunk (690 = 3*230)

__global__ __launch_bounds__(256) void out_gemm_kernel(
        const float* __restrict__ repre,
        const float* __restrict__ rel,
        const float* __restrict__ bias,
        float*       __restrict__ out) {
    __shared__ float s_rel[NCLS * K3_CD];   // 48,760 B

    const int t     = threadIdx.x;
    const int co    = t & 7;
    const int bag_l = t >> 3;
    const int bag   = blockIdx.x * K3_BPB + bag_l;

    float acc[7];
#pragma unroll
    for (int k = 0; k < 7; ++k) acc[k] = 0.f;

    for (int chunk = 0; chunk < 3; ++chunk) {
        const int d0 = chunk * K3_CD;
        // stage rel[:, d0:d0+230] into LDS (coalesced)
        for (int idx = t; idx < NCLS * K3_CD; idx += 256) {
            const int row = idx / K3_CD;
            const int col = idx - row * K3_CD;
            s_rel[idx] = rel[(size_t)row * DIM + d0 + col];
        }
        __syncthreads();

        const float2* rep2 = (const float2*)(repre + (size_t)bag * DIM + d0);
        const float2* srl2 = (const float2*)s_rel;
        for (int d2 = 0; d2 < K3_CD / 2; ++d2) {
            const float2 xd = rep2[d2];
#pragma unroll
            for (int k = 0; k < 7; ++k) {
                const int c = co + 8 * k;
                if (c < NCLS) {
                    const float2 rv = srl2[c * (K3_CD / 2) + d2];
                    acc[k] += xd.x * rv.x + xd.y * rv.y;
                }
            }
        }
        __syncthreads();
    }

#pragma unroll
    for (int k = 0; k < 7; ++k) {
        const int c = co + 8 * k;
        if (c < NCLS) out[(size_t)bag * NCLS + c] = acc[k] + bias[c];
    }
}

// ---------------------------------------------------------------------------
// Fallback (ws too small): round-1 single-kernel version, one bag per block.
// ---------------------------------------------------------------------------
__global__ __launch_bounds__(256) void bag_attn_fallback(
        const float* __restrict__ x,
        const float* __restrict__ rel,
        const float* __restrict__ att,
        const float* __restrict__ bias,
        const int*   __restrict__ query,
        const int*   __restrict__ scope,
        float*       __restrict__ out) {
    const int b    = blockIdx.x;
    const int tid  = threadIdx.x;
    const int wave = tid >> 6;
    const int lane = tid & 63;
    const int start = scope[b];
    const int end   = scope[b + 1];

    float2 acc[6];
#pragma unroll
    for (int k = 0; k < 6; ++k) acc[k] = make_float2(0.f, 0.f);
    float m = -INFINITY, l = 0.f;

    for (int i = start + wave; i < end; i += 4) {
        const float2* xrow = (const float2*)(x + (size_t)i * DIM);
        const int q = query[i];
        const float2* rrow = (const float2*)(rel + (size_t)q * DIM);
        const float2* arow = (const float2*)(att + (size_t)q * DIM);
        float2 xv[6];
        float partial = 0.f;
#pragma unroll
        for (int k = 0; k < 6; ++k) {
            const int p = lane + 64 * k;
            if (p < PAIRS) {
                xv[k] = xrow[p];
                const float2 rv = rrow[p];
                const float2 av = arow[p];
                partial += xv[k].x * rv.x * av.x + xv[k].y * rv.y * av.y;
            } else xv[k] = make_float2(0.f, 0.f);
        }
#pragma unroll
        for (int off = 32; off >= 1; off >>= 1)
            partial += __shfl_xor(partial, off, 64);
        const float mn = fmaxf(m, partial);
        const float sc = __expf(m - mn);
        const float e  = __expf(partial - mn);
        l = l * sc + e;
#pragma unroll
        for (int k = 0; k < 6; ++k) {
            acc[k].x = acc[k].x * sc + e * xv[k].x;
            acc[k].y = acc[k].y * sc + e * xv[k].y;
        }
        m = mn;
    }

    __shared__ float s_m[4], s_l[4];
    __shared__ float s_acc[4][DIM];
    __shared__ float s_rep[DIM];
    if (lane == 0) { s_m[wave] = m; s_l[wave] = l; }
    __syncthreads();
    const float M = fmaxf(fmaxf(s_m[0], s_m[1]), fmaxf(s_m[2], s_m[3]));
    const float factor = (l > 0.f) ? __expf(m - M) : 0.f;
#pragma unroll
    for (int k = 0; k < 6; ++k) {
        const int p = lane + 64 * k;
        if (p < PAIRS) {
            s_acc[wave][2 * p]     = acc[k].x * factor;
            s_acc[wave][2 * p + 1] = acc[k].y * factor;
        }
    }
    __syncthreads();
    float Ltot = 0.f;
#pragma unroll
    for (int w = 0; w < 4; ++w) {
        const float fw = (s_l[w] > 0.f) ? __expf(s_m[w] - M) : 0.f;
        Ltot += s_l[w] * fw;
    }
    const float inv = 1.f / Ltot;
    for (int d = tid; d < DIM; d += 256)
        s_rep[d] = (s_acc[0][d] + s_acc[1][d] + s_acc[2][d] + s_acc[3][d]) * inv;
    __syncthreads();
    for (int c = wave; c < NCLS; c += 4) {
        const float2* rrow = (const float2*)(rel + (size_t)c * DIM);
        float partial = 0.f;
#pragma unroll
        for (int k = 0; k < 6; ++k) {
            const int p = lane + 64 * k;
            if (p < PAIRS)
                partial += rrow[p].x * s_rep[2 * p] + rrow[p].y * s_rep[2 * p + 1];
        }
#pragma unroll
        for (int off = 32; off >= 1; off >>= 1)
            partial += __shfl_xor(partial, off, 64);
        if (lane == 0) out[(size_t)b * NCLS + c] = partial + bias[c];
    }
}

extern "C" void kernel_launch(void* const* d_in, const int* in_sizes, int n_in,
                              void* d_out, int out_size, void* d_ws, size_t ws_size,
                              hipStream_t stream) {
    const float* x     = (const float*)d_in[0];   // [131072, 690]
    const float* rel   = (const float*)d_in[1];   // [53, 690]
    const float* att   = (const float*)d_in[2];   // [53, 690]
    const float* bias  = (const float*)d_in[3];   // [53]
    const int*   query = (const int*)d_in[4];     // [131072]
    const int*   scope = (const int*)d_in[5];     // [8193]
    float*       out   = (float*)d_out;           // [8192, 53]

    const size_t comb_bytes  = (size_t)NCLS * DIM * sizeof(float);     // 146,280
    const size_t comb_pad    = (comb_bytes + 255) & ~(size_t)255;      // 146,432
    const size_t repre_bytes = (size_t)NBAGS * DIM * sizeof(float);    // 22.6 MB

    if (ws_size >= comb_pad + repre_bytes) {
        float* comb  = (float*)d_ws;
        float* repre = (float*)((char*)d_ws + comb_pad);
        comb_kernel<<<(NCLS * DIM + 255) / 256, 256, 0, stream>>>(att, rel, comb);
        bag_stream_kernel<<<NBAGS / 4, 256, 0, stream>>>(x, comb, query, scope, repre);
        out_gemm_kernel<<<NBAGS / K3_BPB, 256, 0, stream>>>(repre, rel, bias, out);
    } else {
        bag_attn_fallback<<<NBAGS, 256, 0, stream>>>(x, rel, att, bias, query, scope, out);
    }
}

// Round 3
// 730.418 us; speedup vs baseline: 1.0935x; 1.0935x over previous
//
#include <hip/hip_runtime.h>
#include <math.h>

// Problem constants (from reference)
#define NSENT 131072
#define NBAGS 8192
#define DIM   690
#define NCLS  53
#define PAIRS 345   // DIM/2 (rows are 8B-aligned: 690*4 = 2760 % 8 == 0)

// ---------------------------------------------------------------------------
// K1: comb[q][d] = att[q][d] * rel[q][d]; also zeroes the bag counter.
// ---------------------------------------------------------------------------
__global__ void comb_kernel(const float* __restrict__ att,
                            const float* __restrict__ rel,
                            float* __restrict__ comb,
                            unsigned int* __restrict__ counter) {
    int i = blockIdx.x * 256 + threadIdx.x;
    if (i < NCLS * DIM) comb[i] = att[i] * rel[i];
    if (blockIdx.x == 0 && threadIdx.x == 0) counter[0] = 0u;
}

// ---------------------------------------------------------------------------
// helpers
// ---------------------------------------------------------------------------
__device__ __forceinline__ void load_row6(float2 dst[6], const float* row, int lane) {
    const float2* r2 = (const float2*)row;
#pragma unroll
    for (int k = 0; k < 6; ++k) {
        const int p = lane + 64 * k;
        dst[k] = (p < PAIRS) ? r2[p] : make_float2(0.f, 0.f);
    }
}

__device__ __forceinline__ float dot_row6(const float2 a[6], const float2 c[6]) {
    // two independent chains to shorten the serial fma dependency
    float s0 = 0.f, s1 = 0.f;
#pragma unroll
    for (int k = 0; k < 6; k += 2) {
        s0 += a[k].x * c[k].x + a[k].y * c[k].y;
        s1 += a[k + 1].x * c[k + 1].x + a[k + 1].y * c[k + 1].y;
    }
    return s0 + s1;
}

// ---------------------------------------------------------------------------
// K2: persistent waves, dynamic bag assignment, flash online softmax.
// Processes 2 sentences/iteration with the next 2 rows prefetched (depth-2),
// ~5.5 KB in flight per wave. No LDS, no barriers.
// ---------------------------------------------------------------------------
__global__ __launch_bounds__(256, 4) void bag_stream_kernel(
        const float* __restrict__ x,
        const float* __restrict__ comb,
        const int*   __restrict__ query,
        const int*   __restrict__ scope,
        float*       __restrict__ repre,
        unsigned int* __restrict__ counter) {
    const int lane = threadIdx.x & 63;

    for (;;) {
        int bag = 0;
        if (lane == 0) bag = (int)atomicAdd(counter, 1u);
        bag = __shfl(bag, 0, 64);
        if (bag >= NBAGS) break;

        const int start = scope[bag];
        const int end   = scope[bag + 1];

        float2 acc[6];
#pragma unroll
        for (int k = 0; k < 6; ++k) acc[k] = make_float2(0.f, 0.f);
        float m = -INFINITY, l = 0.f;

        float2 xa[6], xb[6];
        int qa = query[start], qb = 0;
        load_row6(xa, x + (size_t)start * DIM, lane);
        if (end - start >= 2) {
            qb = query[start + 1];
            load_row6(xb, x + (size_t)(start + 1) * DIM, lane);
        }

        int i = start;
        while (i + 2 <= end) {
            const int j = i + 2;
            const bool p1 = (j < end);
            const bool p2 = (j + 1 < end);

            // prefetch next pair of x rows (the HBM-latency critical loads)
            float2 xn1[6], xn2[6];
            int qn1 = qa, qn2 = qb;
            if (p1) { qn1 = query[j];     load_row6(xn1, x + (size_t)j * DIM, lane); }
            if (p2) { qn2 = query[j + 1]; load_row6(xn2, x + (size_t)(j + 1) * DIM, lane); }

            // comb rows are L2-hot (146 KB table)
            float2 ca[6], cb[6];
            load_row6(ca, comb + (size_t)qa * DIM, lane);
            load_row6(cb, comb + (size_t)qb * DIM, lane);

            float pa = dot_row6(xa, ca);
            float pb = dot_row6(xb, cb);
#pragma unroll
            for (int off = 32; off >= 1; off >>= 1) {
                pa += __shfl_xor(pa, off, 64);
                pb += __shfl_xor(pb, off, 64);
            }

            const float mn = fmaxf(m, fmaxf(pa, pb));
            const float sc = __expf(m - mn);
            const float ea = __expf(pa - mn);
            const float eb = __expf(pb - mn);
            l = l * sc + ea + eb;
#pragma unroll
            for (int k = 0; k < 6; ++k) {
                acc[k].x = acc[k].x * sc + ea * xa[k].x + eb * xb[k].x;
                acc[k].y = acc[k].y * sc + ea * xa[k].y + eb * xb[k].y;
            }
            m = mn;

            if (p1) {
                qa = qn1;
#pragma unroll
                for (int k = 0; k < 6; ++k) xa[k] = xn1[k];
            }
            if (p2) {
                qb = qn2;
#pragma unroll
                for (int k = 0; k < 6; ++k) xb[k] = xn2[k];
            }
            i = j;
        }

        if (i < end) {  // one remaining sentence, already in (xa, qa)
            float2 ca[6];
            load_row6(ca, comb + (size_t)qa * DIM, lane);
            float pa = dot_row6(xa, ca);
#pragma unroll
            for (int off = 32; off >= 1; off >>= 1)
                pa += __shfl_xor(pa, off, 64);
            const float mn = fmaxf(m, pa);
            const float sc = __expf(m - mn);
            const float ea = __expf(pa - mn);
            l = l * sc + ea;
#pragma unroll
            for (int k = 0; k < 6; ++k) {
                acc[k].x = acc[k].x * sc + ea * xa[k].x;
                acc[k].y = acc[k].y * sc + ea * xa[k].y;
            }
        }

        const float inv = 1.f / l;
        float2* rrow = (float2*)(repre + (size_t)bag * DIM);
#pragma unroll
        for (int k = 0; k < 6; ++k) {
            const int p = lane + 64 * k;
            if (p < PAIRS)
                rrow[p] = make_float2(acc[k].x * inv, acc[k].y * inv);
        }
    }
}

// ---------------------------------------------------------------------------
// K3: out[b][c] = dot(repre[b], rel[c]) + bias[c]
// 32 bags/block, rel staged in LDS in 3 chunks of [53][230] (48.8 KB).
// ---------------------------------------------------------------------------
#define K3_BPB 32
#define K3_CD  230

__global__ __launch_bounds__(256) void out_gemm_kernel(
        const float* __restrict__ repre,
        const float* __restrict__ rel,
        const float* __restrict__ bias,
        float*       __restrict__ out) {
    __shared__ float s_rel[NCLS * K3_CD];

    const int t     = threadIdx.x;
    const int co    = t & 7;
    const int bag_l = t >> 3;
    const int bag   = blockIdx.x * K3_BPB + bag_l;

    float acc[7];
#pragma unroll
    for (int k = 0; k < 7; ++k) acc[k] = 0.f;

    for (int chunk = 0; chunk < 3; ++chunk) {
        const int d0 = chunk * K3_CD;
        for (int idx = t; idx < NCLS * K3_CD; idx += 256) {
            const int row = idx / K3_CD;
            const int col = idx - row * K3_CD;
            s_rel[idx] = rel[(size_t)row * DIM + d0 + col];
        }
        __syncthreads();

        const float2* rep2 = (const float2*)(repre + (size_t)bag * DIM + d0);
        const float2* srl2 = (const float2*)s_rel;
        for (int d2 = 0; d2 < K3_CD / 2; ++d2) {
            const float2 xd = rep2[d2];
#pragma unroll
            for (int k = 0; k < 7; ++k) {
                const int c = co + 8 * k;
                if (c < NCLS) {
                    const float2 rv = srl2[c * (K3_CD / 2) + d2];
                    acc[k] += xd.x * rv.x + xd.y * rv.y;
                }
            }
        }
        __syncthreads();
    }

#pragma unroll
    for (int k = 0; k < 7; ++k) {
        const int c = co + 8 * k;
        if (c < NCLS) out[(size_t)bag * NCLS + c] = acc[k] + bias[c];
    }
}

// ---------------------------------------------------------------------------
// Fallback (ws too small): round-1 single-kernel version.
// ---------------------------------------------------------------------------
__global__ __launch_bounds__(256) void bag_attn_fallback(
        const float* __restrict__ x,
        const float* __restrict__ rel,
        const float* __restrict__ att,
        const float* __restrict__ bias,
        const int*   __restrict__ query,
        const int*   __restrict__ scope,
        float*       __restrict__ out) {
    const int b    = blockIdx.x;
    const int tid  = threadIdx.x;
    const int wave = tid >> 6;
    const int lane = tid & 63;
    const int start = scope[b];
    const int end   = scope[b + 1];

    float2 acc[6];
#pragma unroll
    for (int k = 0; k < 6; ++k) acc[k] = make_float2(0.f, 0.f);
    float m = -INFINITY, l = 0.f;

    for (int i = start + wave; i < end; i += 4) {
        const float2* xrow = (const float2*)(x + (size_t)i * DIM);
        const int q = query[i];
        const float2* rrow = (const float2*)(rel + (size_t)q * DIM);
        const float2* arow = (const float2*)(att + (size_t)q * DIM);
        float2 xv[6];
        float partial = 0.f;
#pragma unroll
        for (int k = 0; k < 6; ++k) {
            const int p = lane + 64 * k;
            if (p < PAIRS) {
                xv[k] = xrow[p];
                partial += xv[k].x * rrow[p].x * arow[p].x + xv[k].y * rrow[p].y * arow[p].y;
            } else xv[k] = make_float2(0.f, 0.f);
        }
#pragma unroll
        for (int off = 32; off >= 1; off >>= 1)
            partial += __shfl_xor(partial, off, 64);
        const float mn = fmaxf(m, partial);
        const float sc = __expf(m - mn);
        const float e  = __expf(partial - mn);
        l = l * sc + e;
#pragma unroll
        for (int k = 0; k < 6; ++k) {
            acc[k].x = acc[k].x * sc + e * xv[k].x;
            acc[k].y = acc[k].y * sc + e * xv[k].y;
        }
        m = mn;
    }

    __shared__ float s_m[4], s_l[4];
    __shared__ float s_acc[4][DIM];
    __shared__ float s_rep[DIM];
    if (lane == 0) { s_m[wave] = m; s_l[wave] = l; }
    __syncthreads();
    const float M = fmaxf(fmaxf(s_m[0], s_m[1]), fmaxf(s_m[2], s_m[3]));
    const float factor = (l > 0.f) ? __expf(m - M) : 0.f;
#pragma unroll
    for (int k = 0; k < 6; ++k) {
        const int p = lane + 64 * k;
        if (p < PAIRS) {
            s_acc[wave][2 * p]     = acc[k].x * factor;
            s_acc[wave][2 * p + 1] = acc[k].y * factor;
        }
    }
    __syncthreads();
    float Ltot = 0.f;
#pragma unroll
    for (int w = 0; w < 4; ++w) {
        const float fw = (s_l[w] > 0.f) ? __expf(s_m[w] - M) : 0.f;
        Ltot += s_l[w] * fw;
    }
    const float inv = 1.f / Ltot;
    for (int d = tid; d < DIM; d += 256)
        s_rep[d] = (s_acc[0][d] + s_acc[1][d] + s_acc[2][d] + s_acc[3][d]) * inv;
    __syncthreads();
    for (int c = wave; c < NCLS; c += 4) {
        const float2* rrow = (const float2*)(rel + (size_t)c * DIM);
        float partial = 0.f;
#pragma unroll
        for (int k = 0; k < 6; ++k) {
            const int p = lane + 64 * k;
            if (p < PAIRS)
                partial += rrow[p].x * s_rep[2 * p] + rrow[p].y * s_rep[2 * p + 1];
        }
#pragma unroll
        for (int off = 32; off >= 1; off >>= 1)
            partial += __shfl_xor(partial, off, 64);
        if (lane == 0) out[(size_t)b * NCLS + c] = partial + bias[c];
    }
}

extern "C" void kernel_launch(void* const* d_in, const int* in_sizes, int n_in,
                              void* d_out, int out_size, void* d_ws, size_t ws_size,
                              hipStream_t stream) {
    const float* x     = (const float*)d_in[0];   // [131072, 690]
    const float* rel   = (const float*)d_in[1];   // [53, 690]
    const float* att   = (const float*)d_in[2];   // [53, 690]
    const float* bias  = (const float*)d_in[3];   // [53]
    const int*   query = (const int*)d_in[4];     // [131072]
    const int*   scope = (const int*)d_in[5];     // [8193]
    float*       out   = (float*)d_out;           // [8192, 53]

    const size_t comb_bytes  = (size_t)NCLS * DIM * sizeof(float);     // 146,280
    const size_t comb_pad    = (comb_bytes + 255) & ~(size_t)255;      // 146,432
    const size_t repre_bytes = (size_t)NBAGS * DIM * sizeof(float);    // 22,609,920

    if (ws_size >= comb_pad + repre_bytes + sizeof(unsigned int)) {
        float*        comb    = (float*)d_ws;
        float*        repre   = (float*)((char*)d_ws + comb_pad);
        unsigned int* counter = (unsigned int*)((char*)d_ws + comb_pad + repre_bytes);
        comb_kernel<<<(NCLS * DIM + 255) / 256, 256, 0, stream>>>(att, rel, comb, counter);
        // 1024 blocks x 4 waves = 4096 persistent waves, dynamic bag assignment
        bag_stream_kernel<<<1024, 256, 0, stream>>>(x, comb, query, scope, repre, counter);
        out_gemm_kernel<<<NBAGS / K3_BPB, 256, 0, stream>>>(repre, rel, bias, out);
    } else {
        bag_attn_fallback<<<NBAGS, 256, 0, stream>>>(x, rel, att, bias, query, scope, out);
    }
}